// Round 5
// baseline (758.387 us; speedup 1.0000x reference)
//
#include <hip/hip_runtime.h>
#include <hip/hip_cooperative_groups.h>

// MultiHeadAttention on MI355X (gfx950).
// R17: ONE cooperative mega-kernel (grid 512x256, exactly 2 blocks/CU) with
// grid.sync() between phases, replacing 5 separate dispatches. Theory: four
// in-kernel probes (bytes R13, occupancy R14, L2 R15, LDS volume R16) were
// all neutral/negative while ISA cost models sum the kernels to ~100-120us
// vs 281us measured -> the dominant remaining term is inter-dispatch
// overhead. Phase bodies are byte-identical to R15 (best, 281.25us):
// prep -> qkv (768 tiles grid-strided) -> attn (R15-exact, pair-fusion of
// R16 REVERTED) -> headnorm -> out_gemm. Shared 36KB arena reused across
// phases. Fallback to the 5-kernel path if cooperative launch fails.

namespace cg = cooperative_groups;

typedef float  f32x4  __attribute__((ext_vector_type(4)));
typedef __bf16 bf16x8 __attribute__((ext_vector_type(8)));
typedef short  s16x4  __attribute__((ext_vector_type(4)));
typedef unsigned short u16;

#define BS 2048
#define DD 512
#define NH 8

__device__ __forceinline__ u16 f2bf(float f) {
  union { float f; unsigned u; } v; v.f = f;
  unsigned r = v.u + 0x7fffu + ((v.u >> 16) & 1u);  // RNE
  return (u16)(r >> 16);
}
__device__ __forceinline__ float bf2f(u16 b) {
  union { unsigned u; float f; } v; v.u = ((unsigned)b) << 16; return v.f;
}
__device__ __forceinline__ u16 cvt1(float f) {
  __bf16 h = (__bf16)f;  // v_cvt (RNE), pairs into v_cvt_pk_bf16_f32
  return __builtin_bit_cast(u16, h);
}

__device__ __forceinline__ void gll16(const u16* g, u16* l) {
  __builtin_amdgcn_global_load_lds((const __attribute__((address_space(1))) void*)g,
                                   (__attribute__((address_space(3))) void*)l, 16, 0, 0);
}

// ---- phase bodies (shared by mega-kernel and fallback wrappers) ----------

__device__ __forceinline__ void prep_body(int tb, int t,
                                          const float* __restrict__ Wq,
                                          const float* __restrict__ Wkv,
                                          const float* __restrict__ Wo,
                                          u16* __restrict__ WqT, u16* __restrict__ WkvT,
                                          u16* __restrict__ WoT, float (*Ts)[65]) {
  const float* W; u16* Wt; int N, ntn;
  if (tb < 64)       { W = Wq;  Wt = WqT;  N = 512;  ntn = 8; }
  else if (tb < 192) { W = Wkv; Wt = WkvT; N = 1024; ntn = 16; tb -= 64; }
  else               { W = Wo;  Wt = WoT;  N = 512;  ntn = 8;  tb -= 192; }
  int tk = tb / ntn, tn = tb - tk * ntn;
  int r = t >> 2, c0 = (t & 3) * 16;
  const float* src = &W[(long)(tk * 64 + r) * N + tn * 64 + c0];
#pragma unroll
  for (int j = 0; j < 4; ++j) {
    float4 x = *(const float4*)(src + j * 4);
    Ts[r][c0 + j * 4 + 0] = x.x; Ts[r][c0 + j * 4 + 1] = x.y;
    Ts[r][c0 + j * 4 + 2] = x.z; Ts[r][c0 + j * 4 + 3] = x.w;
  }
  __syncthreads();
  u16* dst = &Wt[(long)(tn * 64 + r) * 512 + tk * 64 + c0];
#pragma unroll
  for (int m = 0; m < 4; ++m) {
    ushort4 o;
    o.x = f2bf(Ts[c0 + m * 4 + 0][r]); o.y = f2bf(Ts[c0 + m * 4 + 1][r]);
    o.z = f2bf(Ts[c0 + m * 4 + 2][r]); o.w = f2bf(Ts[c0 + m * 4 + 3][r]);
    *(ushort4*)(dst + m * 4) = o;
  }
}

// ---- GEMM core, BK=64 (two 32-col panels per barrier) -------------------
template <int AF32>
__device__ __forceinline__ void gemm_core64(const void* __restrict__ Av,
                                            const u16* __restrict__ Bt,
                                            int m0, int n0, int K,
                                            u16* Al, u16* Bl, f32x4 acc[4][4]) {
  const int t = threadIdx.x;
  const int wv = t >> 6, ln = t & 63, qd = ln >> 4, l16 = ln & 15;
  const int rw = (wv & 1) * 64, cw = (wv >> 1) * 64;
  const int srB = wv * 16 + (ln >> 2), scB = (ln & 3) * 8;  // gll mapping
  const int srA = t >> 1, scA = (t & 1) * 16;               // f32 stage mapping
  for (int k0 = 0; k0 < K; k0 += 64) {
    __syncthreads();
    if (AF32) {
      const float* Af = (const float*)Av;
#pragma unroll
      for (int p = 0; p < 2; ++p) {
        const float* src = &Af[(long)(m0 + srA) * K + k0 + p * 32 + scA];
        float4 x0 = *(const float4*)src;
        float4 x1 = *(const float4*)(src + 4);
        float4 x2 = *(const float4*)(src + 8);
        float4 x3 = *(const float4*)(src + 12);
        bf16x8 o0, o1;
        o0[0] = (__bf16)x0.x; o0[1] = (__bf16)x0.y; o0[2] = (__bf16)x0.z; o0[3] = (__bf16)x0.w;
        o0[4] = (__bf16)x1.x; o0[5] = (__bf16)x1.y; o0[6] = (__bf16)x1.z; o0[7] = (__bf16)x1.w;
        o1[0] = (__bf16)x2.x; o1[1] = (__bf16)x2.y; o1[2] = (__bf16)x2.z; o1[3] = (__bf16)x2.w;
        o1[4] = (__bf16)x3.x; o1[5] = (__bf16)x3.y; o1[6] = (__bf16)x3.z; o1[7] = (__bf16)x3.w;
        u16* dst = &Al[p * 4096 + srA * 32 + scA];
        *(bf16x8*)dst = o0;
        *(bf16x8*)(dst + 8) = o1;
      }
    } else {
      const u16* Ab = (const u16*)Av;
#pragma unroll
      for (int p = 0; p < 2; ++p)
#pragma unroll
        for (int c = 0; c < 2; ++c) {
          int r = c * 64 + srB;
          gll16(&Ab[(long)(m0 + r) * K + k0 + p * 32 + scB], &Al[p * 4096 + r * 32 + scB]);
        }
    }
#pragma unroll
    for (int p = 0; p < 2; ++p)
#pragma unroll
      for (int c = 0; c < 2; ++c) {
        int r = c * 64 + srB;
        gll16(&Bt[(long)(n0 + r) * K + k0 + p * 32 + scB], &Bl[p * 4096 + r * 32 + scB]);
      }
    __syncthreads();
#pragma unroll
    for (int p = 0; p < 2; ++p) {
      bf16x8 af[4], bfr[4];
#pragma unroll
      for (int i = 0; i < 4; ++i)
        af[i] = *(const bf16x8*)&Al[p * 4096 + (rw + i * 16 + l16) * 32 + qd * 8];
#pragma unroll
      for (int j = 0; j < 4; ++j)
        bfr[j] = *(const bf16x8*)&Bl[p * 4096 + (cw + j * 16 + l16) * 32 + qd * 8];
#pragma unroll
      for (int i = 0; i < 4; ++i)
#pragma unroll
        for (int j = 0; j < 4; ++j)
          acc[i][j] = __builtin_amdgcn_mfma_f32_16x16x32_bf16(af[i], bfr[j], acc[i][j], 0, 0, 0);
    }
  }
}

__device__ __forceinline__ void qkv_tile(int bx, int by,
                                         const float* __restrict__ query,
                                         const float* __restrict__ value,
                                         const u16* __restrict__ WqT,
                                         const u16* __restrict__ WkvT,
                                         u16* __restrict__ Qb, u16* __restrict__ Kb,
                                         u16* __restrict__ Vt, u16* Al, u16* Bl) {
  const bool isQ = by < 4;
  const void* A = isQ ? (const void*)query : (const void*)value;
  const u16* Bt = isQ ? WqT : WkvT;
  const int n0 = (isQ ? by : by - 4) * 128;
  const int m0 = bx * 128;
  f32x4 acc[4][4] = {};
  gemm_core64<1>(A, Bt, m0, n0, 512, Al, Bl, acc);
  const int t = threadIdx.x;
  const int wv = t >> 6, ln = t & 63, qd = ln >> 4, l16 = ln & 15;
  const int rw = (wv & 1) * 64, cw = (wv >> 1) * 64;
  if (isQ) {
#pragma unroll
    for (int i = 0; i < 4; ++i)
#pragma unroll
      for (int j = 0; j < 4; ++j) {
        int row = m0 + rw + i * 16 + qd * 4, col = n0 + cw + j * 16 + l16;
#pragma unroll
        for (int r = 0; r < 4; ++r)
          Qb[(long)(row + r) * 512 + col] = cvt1(acc[i][j][r]);
      }
  } else {
#pragma unroll
    for (int j = 0; j < 4; ++j) {
      int col = n0 + cw + j * 16 + l16;
      if (col < 512) {
#pragma unroll
        for (int i = 0; i < 4; ++i) {
          int row = m0 + rw + i * 16 + qd * 4;
#pragma unroll
          for (int r = 0; r < 4; ++r)
            Kb[(long)(row + r) * 512 + col] = cvt1(acc[i][j][r]);
        }
      } else {
        int c2 = col - 512, hh = c2 >> 6, dd = c2 & 63;
#pragma unroll
        for (int i = 0; i < 4; ++i) {
          int sg = m0 + rw + i * 16 + qd * 4;
          int bb = sg >> 11, ss = sg & 2047;
          ushort4 o;
          o.x = cvt1(acc[i][j][0]); o.y = cvt1(acc[i][j][1]);
          o.z = cvt1(acc[i][j][2]); o.w = cvt1(acc[i][j][3]);
          *(ushort4*)&Vt[((long)(bb * 8 + hh) * 64 + dd) * 2048 + ss] = o;
        }
      }
    }
  }
}

__device__ __forceinline__ void out_tile(int bx, int by,
                                         const u16* __restrict__ A,
                                         const u16* __restrict__ Bt,
                                         float* __restrict__ C, u16* Al, u16* Bl) {
  const int m0 = bx * 128, n0 = by * 128;
  f32x4 acc[4][4] = {};
  gemm_core64<0>(A, Bt, m0, n0, 512, Al, Bl, acc);
  const int t = threadIdx.x;
  const int wv = t >> 6, ln = t & 63, qd = ln >> 4, l16 = ln & 15;
  const int rw = (wv & 1) * 64, cw = (wv >> 1) * 64;
#pragma unroll
  for (int i = 0; i < 4; ++i)
#pragma unroll
    for (int j = 0; j < 4; ++j) {
      int row = m0 + rw + i * 16 + qd * 4, col = n0 + cw + j * 16 + l16;
#pragma unroll
      for (int r = 0; r < 4; ++r)
        C[(long)(row + r) * 512 + col] = acc[i][j][r];
    }
}

// one q-tile compute phase against the staged K/V chunk
__device__ __forceinline__ void attn_phase(const u16* ks, const u16* vs,
                                           const bf16x8 bq[2], f32x4 o[4],
                                           float& l_i, float scale2, bool diag,
                                           int wv, int qd, int l16) {
  constexpr int ST = 72;
  f32x4 s[4] = {};
#pragma unroll
  for (int c = 0; c < 2; ++c)
#pragma unroll
    for (int nt = 0; nt < 4; ++nt) {
      bf16x8 ak = *(const bf16x8*)&ks[(nt * 16 + l16) * ST + c * 32 + qd * 8];
      s[nt] = __builtin_amdgcn_mfma_f32_16x16x32_bf16(ak, bq[c], s[nt], 0, 0, 0);
    }
  if (diag) {
    const int limi = wv * 16 + l16;
#pragma unroll
    for (int nt = 0; nt < 4; ++nt)
#pragma unroll
      for (int r = 0; r < 4; ++r) {
        float v = s[nt][r] * scale2;
        if (nt * 16 + qd * 4 + r > limi) v = -INFINITY;
        float p = exp2f(v);
        s[nt][r] = p;
        l_i += p;
      }
  } else {
#pragma unroll
    for (int nt = 0; nt < 4; ++nt)
#pragma unroll
      for (int r = 0; r < 4; ++r) {
        float p = exp2f(s[nt][r] * scale2);
        s[nt][r] = p;
        l_i += p;
      }
  }
#pragma unroll
  for (int cp = 0; cp < 2; ++cp) {
    bf16x8 pb;
#pragma unroll
    for (int j = 0; j < 4; ++j) {
      pb[j] = (__bf16)s[cp * 2][j];
      pb[4 + j] = (__bf16)s[cp * 2 + 1][j];
    }
#pragma unroll
    for (int n2 = 0; n2 < 4; ++n2) {
      bf16x8 av;
      s16x4* ah = (s16x4*)&av;
      const u16* vp = &vs[(n2 * 16 + l16) * ST + cp * 32 + qd * 4];
      ah[0] = *(const s16x4*)vp;
      ah[1] = *(const s16x4*)(vp + 16);
      o[n2] = __builtin_amdgcn_mfma_f32_16x16x32_bf16(av, pb, o[n2], 0, 0, 0);
    }
  }
}

// merged-pair flash attention block, R15-exact; KsB/VtsB are 2x(64*72) u16
__device__ __forceinline__ void attn_block(int bid,
                                           const u16* __restrict__ Qb,
                                           const u16* __restrict__ Kb,
                                           const u16* __restrict__ Vt,
                                           u16* __restrict__ heads, float scale2,
                                           u16* KsB, u16* VtsB) {
  constexpr int ST = 72;
  constexpr int BUF = 64 * ST;
  const int t = threadIdx.x;
  const int wv = t >> 6, ln = t & 63, qd = ln >> 4, l16 = ln & 15;
  const int sr = t >> 2, scg = (t & 3) * 16;
  const int hb = (bid & 7) + 8 * (bid >> 7);
  const int qtS = (bid >> 3) & 15, qtL = 31 - qtS;
  const int h = hb & 7, b = hb >> 3;
  const int bs0 = b * BS;
  const u16* vtb = Vt + ((long)(b * 8 + h) * 64) * 2048;

  bf16x8 bqS[2], bqL[2];
#pragma unroll
  for (int c = 0; c < 2; ++c) {
    bqS[c] = *(const bf16x8*)&Qb[(long)(bs0 + qtS * 64 + wv * 16 + l16) * 512 + h * 64 + c * 32 + qd * 8];
    bqL[c] = *(const bf16x8*)&Qb[(long)(bs0 + qtL * 64 + wv * 16 + l16) * 512 + h * 64 + c * 32 + qd * 8];
  }

  bf16x8 kr0, kr1, vr0, vr1;
#define FETCH(KB) do { \
    const u16* kp_ = &Kb[(long)(bs0 + (KB) * 64 + sr) * 512 + h * 64 + scg]; \
    kr0 = *(const bf16x8*)kp_; kr1 = *(const bf16x8*)(kp_ + 8); \
    const u16* vp_ = &vtb[(long)sr * 2048 + (KB) * 64 + scg]; \
    vr0 = *(const bf16x8*)vp_; vr1 = *(const bf16x8*)(vp_ + 8); } while (0)
  FETCH(0);
  float lS = 0.f, lL = 0.f;
  f32x4 oS[4] = {}, oL[4] = {};

  for (int kb = 0; kb <= qtL; ++kb) {
    u16* Ksb = KsB + (kb & 1) * BUF;
    u16* Vtsb = VtsB + (kb & 1) * BUF;
    *(bf16x8*)&Ksb[sr * ST + scg] = kr0;
    *(bf16x8*)&Ksb[sr * ST + scg + 8] = kr1;
    *(bf16x8*)&Vtsb[sr * ST + scg] = vr0;
    *(bf16x8*)&Vtsb[sr * ST + scg + 8] = vr1;
    __syncthreads();  // single barrier: 2-buffer protocol covers WAR hazard
    if (kb < qtL) FETCH(kb + 1);  // in flight during compute below

    attn_phase(Ksb, Vtsb, bqL, oL, lL, scale2, kb == qtL, wv, qd, l16);
    if (kb <= qtS)
      attn_phase(Ksb, Vtsb, bqS, oS, lS, scale2, kb == qtS, wv, qd, l16);
  }
#undef FETCH

  // epilogue: both tiles (L -> KsB scratch, S -> VtsB scratch)
  lL += __shfl_xor(lL, 16); lL += __shfl_xor(lL, 32);
  lS += __shfl_xor(lS, 16); lS += __shfl_xor(lS, 32);
  float invL = 1.f / lL, invS = 1.f / lS;
  __syncthreads();
#pragma unroll
  for (int n2 = 0; n2 < 4; ++n2)
#pragma unroll
    for (int r = 0; r < 4; ++r) {
      KsB[(wv * 16 + l16) * ST + n2 * 16 + qd * 4 + r] = cvt1(oL[n2][r] * invL);
      VtsB[(wv * 16 + l16) * ST + n2 * 16 + qd * 4 + r] = cvt1(oS[n2][r] * invS);
    }
  __syncthreads();
  {
    u16* dstL = &heads[(long)(bs0 + qtL * 64 + sr) * 512 + h * 64 + scg];
    *(bf16x8*)dstL = *(const bf16x8*)&KsB[sr * ST + scg];
    *(bf16x8*)(dstL + 8) = *(const bf16x8*)&KsB[sr * ST + scg + 8];
    u16* dstS = &heads[(long)(bs0 + qtS * 64 + sr) * 512 + h * 64 + scg];
    *(bf16x8*)dstS = *(const bf16x8*)&VtsB[sr * ST + scg];
    *(bf16x8*)(dstS + 8) = *(const bf16x8*)&VtsB[sr * ST + scg + 8];
  }
}

__device__ __forceinline__ void headnorm_i(int i, const u16* __restrict__ heads,
                                           const float* __restrict__ hm,
                                           u16* __restrict__ outn) {
  int d = i & 63, bs = i >> 6;
  const u16* p = heads + (long)bs * DD + d;
  float x[NH], mean = 0.f;
#pragma unroll
  for (int h = 0; h < NH; ++h) { x[h] = bf2f(p[h * 64]); mean += x[h]; }
  mean *= 0.125f;
  float var = 0.f;
#pragma unroll
  for (int h = 0; h < NH; ++h) { float dd = x[h] - mean; var += dd * dd; }
  var *= 0.125f;
  float inv = 1.f / (sqrtf(var) + 0.01f);
#pragma unroll
  for (int h = 0; h < NH; ++h)
    outn[(long)bs * DD + h * 64 + d] = cvt1((x[h] - mean) * inv * hm[h]);
}

// ---- cooperative mega-kernel --------------------------------------------
__global__ __launch_bounds__(256, 2) void fused(const float* __restrict__ query,
                                                const float* __restrict__ value,
                                                const float* __restrict__ Wq,
                                                const float* __restrict__ Wkv,
                                                const float* __restrict__ Wo,
                                                const float* __restrict__ normp,
                                                const float* __restrict__ hmult,
                                                u16* __restrict__ WqT,
                                                u16* __restrict__ WkvT,
                                                u16* __restrict__ WoT,
                                                u16* __restrict__ Qb,
                                                u16* __restrict__ Kb,
                                                u16* __restrict__ Vt,
                                                u16* __restrict__ heads,
                                                u16* __restrict__ hN,
                                                float* __restrict__ out) {
  // 36KB arena: attn = 2x(2*4608) u16; gemm = Al(16KB)+Bl(16KB); prep Ts 16.6KB
  __shared__ __align__(16) unsigned char smraw[36864];
  const int t = threadIdx.x;
  const int bid = blockIdx.x;
  cg::grid_group grid = cg::this_grid();
  const float scale2 = normp[0] * 1.44269504f;  // log2 e

  // phase 0: weight transposes (256 logical blocks)
  if (bid < 256)
    prep_body(bid, t, Wq, Wkv, Wo, WqT, WkvT, WoT, (float(*)[65])smraw);
  __threadfence();
  grid.sync();

  // phase 1: qkv GEMM, 768 tiles grid-strided over 512 blocks
  {
    u16* Al = (u16*)smraw;
    u16* Bl = (u16*)(smraw + 16384);
    for (int tile = bid; tile < 768; tile += 512)
      qkv_tile(tile & 63, tile >> 6, query, value, WqT, WkvT, Qb, Kb, Vt, Al, Bl);
  }
  __threadfence();
  grid.sync();

  // phase 2: flash attention, 1:1 with blocks
  attn_block(bid, Qb, Kb, Vt, heads, scale2, (u16*)smraw, (u16*)(smraw + 18432));
  __threadfence();
  grid.sync();

  // phase 3: cross-head norm, 524288 elems grid-strided
  for (int i = bid * 256 + t; i < 4 * BS * 64; i += 512 * 256)
    headnorm_i(i, heads, hmult, hN);
  __threadfence();
  grid.sync();

  // phase 4: output GEMM, 256 tiles
  if (bid < 256) {
    u16* Al = (u16*)smraw;
    u16* Bl = (u16*)(smraw + 16384);
    out_tile(bid & 63, bid >> 6, hN, WoT, out, Al, Bl);
  }
}

// ---- fallback wrappers (5-kernel path, R15-identical) --------------------
__global__ __launch_bounds__(256) void prep(const float* __restrict__ Wq,
                                            const float* __restrict__ Wkv,
                                            const float* __restrict__ Wo,
                                            u16* __restrict__ WqT, u16* __restrict__ WkvT,
                                            u16* __restrict__ WoT) {
  __shared__ float Ts[64][65];
  prep_body(blockIdx.x, threadIdx.x, Wq, Wkv, Wo, WqT, WkvT, WoT, Ts);
}

__global__ __launch_bounds__(256) void qkv_gemm(const float* __restrict__ query,
                                                const float* __restrict__ value,
                                                const u16* __restrict__ WqT,
                                                const u16* __restrict__ WkvT,
                                                u16* __restrict__ Qb,
                                                u16* __restrict__ Kb,
                                                u16* __restrict__ Vt) {
  __shared__ __align__(16) u16 Al[2 * 128 * 32];
  __shared__ __align__(16) u16 Bl[2 * 128 * 32];
  qkv_tile(blockIdx.x, blockIdx.y, query, value, WqT, WkvT, Qb, Kb, Vt, Al, Bl);
}

__global__ __launch_bounds__(256, 2) void attn(const u16* __restrict__ Qb,
                                               const u16* __restrict__ Kb,
                                               const u16* __restrict__ Vt,
                                               u16* __restrict__ heads,
                                               const float* __restrict__ normp) {
  __shared__ __align__(16) u16 KsB[2 * 64 * 72];
  __shared__ __align__(16) u16 VtsB[2 * 64 * 72];
  attn_block(blockIdx.x, Qb, Kb, Vt, heads, normp[0] * 1.44269504f, KsB, VtsB);
}

__global__ __launch_bounds__(256) void headnorm(const u16* __restrict__ heads,
                                                const float* __restrict__ hm,
                                                u16* __restrict__ outn) {
  headnorm_i(blockIdx.x * 256 + threadIdx.x, heads, hm, outn);
}

__global__ __launch_bounds__(256) void out_gemm(const u16* __restrict__ A,
                                                const u16* __restrict__ Bt,
                                                float* __restrict__ C) {
  __shared__ __align__(16) u16 Al[2 * 128 * 32];
  __shared__ __align__(16) u16 Bl[2 * 128 * 32];
  out_tile(blockIdx.x, blockIdx.y, A, Bt, C, Al, Bl);
}

extern "C" void kernel_launch(void* const* d_in, const int* in_sizes, int n_in,
                              void* d_out, int out_size, void* d_ws, size_t ws_size,
                              hipStream_t stream) {
  const float* query = (const float*)d_in[0];
  const float* value = (const float*)d_in[1];
  // d_in[2] = mask: causal by construction -> applied analytically
  const float* Wq    = (const float*)d_in[3];
  const float* Wkv   = (const float*)d_in[4];
  const float* Wo    = (const float*)d_in[5];
  const float* normp = (const float*)d_in[6];
  const float* hmult = (const float*)d_in[7];

  char* ws = (char*)d_ws;
  const size_t MB = 1 << 20;
  u16*   WqT   = (u16*)(ws);                   //  0.5 MB
  u16*   WkvT  = (u16*)(ws + 524288);          //  1 MB
  u16*   WoT   = (u16*)(ws + 1 * MB + 524288); //  0.5 MB
  u16*   Qb    = (u16*)(ws + 2 * MB);          //  8 MB
  u16*   Kb    = (u16*)(ws + 10 * MB);         //  8 MB
  u16*   Vt    = (u16*)(ws + 18 * MB);         //  8 MB
  u16*   heads = (u16*)(ws + 26 * MB);         //  8 MB
  u16*   hN    = (u16*)(ws + 34 * MB);         //  8 MB (42 MB total)
  float* outf  = (float*)d_out;

  void* args[] = {(void*)&query, (void*)&value, (void*)&Wq, (void*)&Wkv, (void*)&Wo,
                  (void*)&normp, (void*)&hmult, (void*)&WqT, (void*)&WkvT, (void*)&WoT,
                  (void*)&Qb, (void*)&Kb, (void*)&Vt, (void*)&heads, (void*)&hN,
                  (void*)&outf};
  hipError_t err = hipLaunchCooperativeKernel((const void*)fused, dim3(512), dim3(256),
                                              args, 0, stream);
  if (err != hipSuccess) {
    // fallback: proven 5-kernel path (R15)
    prep<<<256, 256, 0, stream>>>(Wq, Wkv, Wo, WqT, WkvT, WoT);
    qkv_gemm<<<dim3(64, 12), 256, 0, stream>>>(query, value, WqT, WkvT, Qb, Kb, Vt);
    attn<<<512, 256, 0, stream>>>(Qb, Kb, Vt, heads, normp);
    headnorm<<<(4 * BS * 64) / 256, 256, 0, stream>>>(heads, hmult, hN);
    out_gemm<<<dim3(64, 4), 256, 0, stream>>>(hN, WoT, outf);
  }
}

// Round 6
// 281.888 us; speedup vs baseline: 2.6904x; 2.6904x over previous
//
#include <hip/hip_runtime.h>

// MultiHeadAttention on MI355X (gfx950).
// R18: R15 (best, 281.25us) + attn super-chunks: stage 128 k-rows per
// barrier into a 4x64-row buffer rotation, run TWO proven attn_phase
// sub-chunks per barrier. Barriers/stagings per block: 24.5 -> ~12.7, and
// each prefetch gets 2 compute phases of latency cover. Phase compute code
// byte-identical; same single-barrier WAR protocol (write bufs(sc+1) are
// disjoint from compute bufs(sc); reuse of bufs(sc) happens only after the
// next barrier). LDS 72KB -> still 2 blocks/CU. R17 evidence: harness fixed
// overhead ~201us, kernels ~80us total; fused/cooperative path abandoned.

typedef float  f32x4  __attribute__((ext_vector_type(4)));
typedef __bf16 bf16x8 __attribute__((ext_vector_type(8)));
typedef short  s16x4  __attribute__((ext_vector_type(4)));
typedef unsigned short u16;

#define BS 2048
#define DD 512
#define NH 8

__device__ __forceinline__ u16 f2bf(float f) {
  union { float f; unsigned u; } v; v.f = f;
  unsigned r = v.u + 0x7fffu + ((v.u >> 16) & 1u);  // RNE
  return (u16)(r >> 16);
}
__device__ __forceinline__ float bf2f(u16 b) {
  union { unsigned u; float f; } v; v.u = ((unsigned)b) << 16; return v.f;
}
__device__ __forceinline__ u16 cvt1(float f) {
  __bf16 h = (__bf16)f;  // v_cvt (RNE), pairs into v_cvt_pk_bf16_f32
  return __builtin_bit_cast(u16, h);
}

__device__ __forceinline__ void gll16(const u16* g, u16* l) {
  __builtin_amdgcn_global_load_lds((const __attribute__((address_space(1))) void*)g,
                                   (__attribute__((address_space(3))) void*)l, 16, 0, 0);
}

// ---- prep: LDS-tiled weight transposes only ------------------------------
__global__ __launch_bounds__(256) void prep(const float* __restrict__ Wq,
                                            const float* __restrict__ Wkv,
                                            const float* __restrict__ Wo,
                                            u16* __restrict__ WqT, u16* __restrict__ WkvT,
                                            u16* __restrict__ WoT) {
  __shared__ float Ts[64][65];
  const int t = threadIdx.x;
  int tb = blockIdx.x;
  const float* W; u16* Wt; int N, ntn;
  if (tb < 64)       { W = Wq;  Wt = WqT;  N = 512;  ntn = 8; }
  else if (tb < 192) { W = Wkv; Wt = WkvT; N = 1024; ntn = 16; tb -= 64; }
  else               { W = Wo;  Wt = WoT;  N = 512;  ntn = 8;  tb -= 192; }
  int tk = tb / ntn, tn = tb - tk * ntn;
  int r = t >> 2, c0 = (t & 3) * 16;
  const float* src = &W[(long)(tk * 64 + r) * N + tn * 64 + c0];
#pragma unroll
  for (int j = 0; j < 4; ++j) {
    float4 x = *(const float4*)(src + j * 4);
    Ts[r][c0 + j * 4 + 0] = x.x; Ts[r][c0 + j * 4 + 1] = x.y;
    Ts[r][c0 + j * 4 + 2] = x.z; Ts[r][c0 + j * 4 + 3] = x.w;
  }
  __syncthreads();
  u16* dst = &Wt[(long)(tn * 64 + r) * 512 + tk * 64 + c0];
#pragma unroll
  for (int m = 0; m < 4; ++m) {
    ushort4 o;
    o.x = f2bf(Ts[c0 + m * 4 + 0][r]); o.y = f2bf(Ts[c0 + m * 4 + 1][r]);
    o.z = f2bf(Ts[c0 + m * 4 + 2][r]); o.w = f2bf(Ts[c0 + m * 4 + 3][r]);
    *(ushort4*)(dst + m * 4) = o;
  }
}

// ---- GEMM core, BK=64 (two 32-col panels per barrier) -------------------
template <int AF32>
__device__ __forceinline__ void gemm_core64(const void* __restrict__ Av,
                                            const u16* __restrict__ Bt,
                                            int m0, int n0, int K,
                                            u16* Al, u16* Bl, f32x4 acc[4][4]) {
  const int t = threadIdx.x;
  const int wv = t >> 6, ln = t & 63, qd = ln >> 4, l16 = ln & 15;
  const int rw = (wv & 1) * 64, cw = (wv >> 1) * 64;
  const int srB = wv * 16 + (ln >> 2), scB = (ln & 3) * 8;  // gll mapping
  const int srA = t >> 1, scA = (t & 1) * 16;               // f32 stage mapping
  for (int k0 = 0; k0 < K; k0 += 64) {
    __syncthreads();
    if (AF32) {
      const float* Af = (const float*)Av;
#pragma unroll
      for (int p = 0; p < 2; ++p) {
        const float* src = &Af[(long)(m0 + srA) * K + k0 + p * 32 + scA];
        float4 x0 = *(const float4*)src;
        float4 x1 = *(const float4*)(src + 4);
        float4 x2 = *(const float4*)(src + 8);
        float4 x3 = *(const float4*)(src + 12);
        bf16x8 o0, o1;
        o0[0] = (__bf16)x0.x; o0[1] = (__bf16)x0.y; o0[2] = (__bf16)x0.z; o0[3] = (__bf16)x0.w;
        o0[4] = (__bf16)x1.x; o0[5] = (__bf16)x1.y; o0[6] = (__bf16)x1.z; o0[7] = (__bf16)x1.w;
        o1[0] = (__bf16)x2.x; o1[1] = (__bf16)x2.y; o1[2] = (__bf16)x2.z; o1[3] = (__bf16)x2.w;
        o1[4] = (__bf16)x3.x; o1[5] = (__bf16)x3.y; o1[6] = (__bf16)x3.z; o1[7] = (__bf16)x3.w;
        u16* dst = &Al[p * 4096 + srA * 32 + scA];
        *(bf16x8*)dst = o0;
        *(bf16x8*)(dst + 8) = o1;
      }
    } else {
      const u16* Ab = (const u16*)Av;
#pragma unroll
      for (int p = 0; p < 2; ++p)
#pragma unroll
        for (int c = 0; c < 2; ++c) {
          int r = c * 64 + srB;
          gll16(&Ab[(long)(m0 + r) * K + k0 + p * 32 + scB], &Al[p * 4096 + r * 32 + scB]);
        }
    }
#pragma unroll
    for (int p = 0; p < 2; ++p)
#pragma unroll
      for (int c = 0; c < 2; ++c) {
        int r = c * 64 + srB;
        gll16(&Bt[(long)(n0 + r) * K + k0 + p * 32 + scB], &Bl[p * 4096 + r * 32 + scB]);
      }
    __syncthreads();
#pragma unroll
    for (int p = 0; p < 2; ++p) {
      bf16x8 af[4], bfr[4];
#pragma unroll
      for (int i = 0; i < 4; ++i)
        af[i] = *(const bf16x8*)&Al[p * 4096 + (rw + i * 16 + l16) * 32 + qd * 8];
#pragma unroll
      for (int j = 0; j < 4; ++j)
        bfr[j] = *(const bf16x8*)&Bl[p * 4096 + (cw + j * 16 + l16) * 32 + qd * 8];
#pragma unroll
      for (int i = 0; i < 4; ++i)
#pragma unroll
        for (int j = 0; j < 4; ++j)
          acc[i][j] = __builtin_amdgcn_mfma_f32_16x16x32_bf16(af[i], bfr[j], acc[i][j], 0, 0, 0);
    }
  }
}

__global__ __launch_bounds__(256) void qkv_gemm(const float* __restrict__ query,
                                                const float* __restrict__ value,
                                                const u16* __restrict__ WqT,
                                                const u16* __restrict__ WkvT,
                                                u16* __restrict__ Qb,
                                                u16* __restrict__ Kb,
                                                u16* __restrict__ Vt) {
  __shared__ __align__(16) u16 Al[2 * 128 * 32];
  __shared__ __align__(16) u16 Bl[2 * 128 * 32];
  const bool isQ = blockIdx.y < 4;
  const void* A = isQ ? (const void*)query : (const void*)value;
  const u16* Bt = isQ ? WqT : WkvT;
  const int n0 = (isQ ? blockIdx.y : blockIdx.y - 4) * 128;
  const int m0 = blockIdx.x * 128;
  f32x4 acc[4][4] = {};
  gemm_core64<1>(A, Bt, m0, n0, 512, Al, Bl, acc);
  const int t = threadIdx.x;
  const int wv = t >> 6, ln = t & 63, qd = ln >> 4, l16 = ln & 15;
  const int rw = (wv & 1) * 64, cw = (wv >> 1) * 64;
  if (isQ) {
#pragma unroll
    for (int i = 0; i < 4; ++i)
#pragma unroll
      for (int j = 0; j < 4; ++j) {
        int row = m0 + rw + i * 16 + qd * 4, col = n0 + cw + j * 16 + l16;
#pragma unroll
        for (int r = 0; r < 4; ++r)
          Qb[(long)(row + r) * 512 + col] = cvt1(acc[i][j][r]);
      }
  } else {
#pragma unroll
    for (int j = 0; j < 4; ++j) {
      int col = n0 + cw + j * 16 + l16;
      if (col < 512) {
#pragma unroll
        for (int i = 0; i < 4; ++i) {
          int row = m0 + rw + i * 16 + qd * 4;
#pragma unroll
          for (int r = 0; r < 4; ++r)
            Kb[(long)(row + r) * 512 + col] = cvt1(acc[i][j][r]);
        }
      } else {
        int c2 = col - 512, hh = c2 >> 6, dd = c2 & 63;
#pragma unroll
        for (int i = 0; i < 4; ++i) {
          int sg = m0 + rw + i * 16 + qd * 4;
          int bb = sg >> 11, ss = sg & 2047;
          ushort4 o;
          o.x = cvt1(acc[i][j][0]); o.y = cvt1(acc[i][j][1]);
          o.z = cvt1(acc[i][j][2]); o.w = cvt1(acc[i][j][3]);
          *(ushort4*)&Vt[((long)(bb * 8 + hh) * 64 + dd) * 2048 + ss] = o;
        }
      }
    }
  }
}

__global__ __launch_bounds__(256) void out_gemm(const u16* __restrict__ A,
                                                const u16* __restrict__ Bt,
                                                float* __restrict__ C) {
  __shared__ __align__(16) u16 Al[2 * 128 * 32];
  __shared__ __align__(16) u16 Bl[2 * 128 * 32];
  const int m0 = blockIdx.x * 128, n0 = blockIdx.y * 128;
  f32x4 acc[4][4] = {};
  gemm_core64<0>(A, Bt, m0, n0, 512, Al, Bl, acc);
  const int t = threadIdx.x;
  const int wv = t >> 6, ln = t & 63, qd = ln >> 4, l16 = ln & 15;
  const int rw = (wv & 1) * 64, cw = (wv >> 1) * 64;
#pragma unroll
  for (int i = 0; i < 4; ++i)
#pragma unroll
    for (int j = 0; j < 4; ++j) {
      int row = m0 + rw + i * 16 + qd * 4, col = n0 + cw + j * 16 + l16;
#pragma unroll
      for (int r = 0; r < 4; ++r)
        C[(long)(row + r) * 512 + col] = acc[i][j][r];
    }
}

// one q-tile compute phase against a staged 64-row K/V chunk (R15-exact)
__device__ __forceinline__ void attn_phase(const u16* ks, const u16* vs,
                                           const bf16x8 bq[2], f32x4 o[4],
                                           float& l_i, float scale2, bool diag,
                                           int wv, int qd, int l16) {
  constexpr int ST = 72;
  f32x4 s[4] = {};
#pragma unroll
  for (int c = 0; c < 2; ++c)
#pragma unroll
    for (int nt = 0; nt < 4; ++nt) {
      bf16x8 ak = *(const bf16x8*)&ks[(nt * 16 + l16) * ST + c * 32 + qd * 8];
      s[nt] = __builtin_amdgcn_mfma_f32_16x16x32_bf16(ak, bq[c], s[nt], 0, 0, 0);
    }
  if (diag) {
    const int limi = wv * 16 + l16;
#pragma unroll
    for (int nt = 0; nt < 4; ++nt)
#pragma unroll
      for (int r = 0; r < 4; ++r) {
        float v = s[nt][r] * scale2;
        if (nt * 16 + qd * 4 + r > limi) v = -INFINITY;
        float p = exp2f(v);
        s[nt][r] = p;
        l_i += p;
      }
  } else {
#pragma unroll
    for (int nt = 0; nt < 4; ++nt)
#pragma unroll
      for (int r = 0; r < 4; ++r) {
        float p = exp2f(s[nt][r] * scale2);
        s[nt][r] = p;
        l_i += p;
      }
  }
#pragma unroll
  for (int cp = 0; cp < 2; ++cp) {
    bf16x8 pb;
#pragma unroll
    for (int j = 0; j < 4; ++j) {
      pb[j] = (__bf16)s[cp * 2][j];
      pb[4 + j] = (__bf16)s[cp * 2 + 1][j];
    }
#pragma unroll
    for (int n2 = 0; n2 < 4; ++n2) {
      bf16x8 av;
      s16x4* ah = (s16x4*)&av;
      const u16* vp = &vs[(n2 * 16 + l16) * ST + cp * 32 + qd * 4];
      ah[0] = *(const s16x4*)vp;
      ah[1] = *(const s16x4*)(vp + 16);
      o[n2] = __builtin_amdgcn_mfma_f32_16x16x32_bf16(av, pb, o[n2], 0, 0, 0);
    }
  }
}

// ---- flash attention: merged-pair, 128-row super-chunks, (256,2) ---------
// Grid 512 (1-D), XCD-gathering decode (R15). Per super-chunk sc: stage
// 128 k-rows into two 64-row buffers (4-buffer rotation), ONE barrier, then
// two attn_phase sub-chunks. Barriers per block: 24.5 -> ~12.7 avg.
__global__ __launch_bounds__(256, 2) void attn(const u16* __restrict__ Qb,
                                               const u16* __restrict__ Kb,
                                               const u16* __restrict__ Vt,
                                               u16* __restrict__ heads,
                                               const float* __restrict__ normp) {
  constexpr int ST = 72;
  constexpr int BUF = 64 * ST;
  __shared__ __align__(16) u16 Ks[4][BUF];
  __shared__ __align__(16) u16 Vts[4][BUF];
  const float scale2 = normp[0] * 1.44269504f;  // log2 e
  const int t = threadIdx.x;
  const int wv = t >> 6, ln = t & 63, qd = ln >> 4, l16 = ln & 15;
  const int sr = t >> 2, scg = (t & 3) * 16;
  const int bid = blockIdx.x;
  const int hb = (bid & 7) + 8 * (bid >> 7);
  const int qtS = (bid >> 3) & 15, qtL = 31 - qtS;
  const int h = hb & 7, b = hb >> 3;
  const int bs0 = b * BS;
  const u16* vtb = Vt + ((long)(b * 8 + h) * 64) * 2048;
  const int scL = qtL >> 1;  // super-chunk count - 1 (qtL is odd: 16..31 -> scL 8..15)

  bf16x8 bqS[2], bqL[2];
#pragma unroll
  for (int c = 0; c < 2; ++c) {
    bqS[c] = *(const bf16x8*)&Qb[(long)(bs0 + qtS * 64 + wv * 16 + l16) * 512 + h * 64 + c * 32 + qd * 8];
    bqL[c] = *(const bf16x8*)&Qb[(long)(bs0 + qtL * 64 + wv * 16 + l16) * 512 + h * 64 + c * 32 + qd * 8];
  }

  // prefetch regs for one 128-row super-chunk: K rows sr, sr+64; V k-cols scg, scg+64
  bf16x8 kr0, kr1, kr2, kr3, vr0, vr1, vr2, vr3;
#define FETCH(SC) do { \
    const u16* kp_ = &Kb[(long)(bs0 + (SC) * 128 + sr) * 512 + h * 64 + scg]; \
    kr0 = *(const bf16x8*)kp_; kr1 = *(const bf16x8*)(kp_ + 8); \
    const u16* kp2_ = kp_ + (long)64 * 512; \
    kr2 = *(const bf16x8*)kp2_; kr3 = *(const bf16x8*)(kp2_ + 8); \
    const u16* vp_ = &vtb[(long)sr * 2048 + (SC) * 128 + scg]; \
    vr0 = *(const bf16x8*)vp_; vr1 = *(const bf16x8*)(vp_ + 8); \
    vr2 = *(const bf16x8*)(vp_ + 64); vr3 = *(const bf16x8*)(vp_ + 72); } while (0)
  FETCH(0);
  float lS = 0.f, lL = 0.f;
  f32x4 oS[4] = {}, oL[4] = {};

  for (int sc = 0; sc <= scL; ++sc) {
    const int sub0 = 2 * sc, sub1 = 2 * sc + 1;
    const int b0 = sub0 & 3, b1 = sub1 & 3;
    *(bf16x8*)&Ks[b0][sr * ST + scg] = kr0;
    *(bf16x8*)&Ks[b0][sr * ST + scg + 8] = kr1;
    *(bf16x8*)&Ks[b1][sr * ST + scg] = kr2;
    *(bf16x8*)&Ks[b1][sr * ST + scg + 8] = kr3;
    *(bf16x8*)&Vts[b0][sr * ST + scg] = vr0;
    *(bf16x8*)&Vts[b0][sr * ST + scg + 8] = vr1;
    *(bf16x8*)&Vts[b1][sr * ST + scg] = vr2;
    *(bf16x8*)&Vts[b1][sr * ST + scg + 8] = vr3;
    __syncthreads();  // 4-buffer rotation: next staging targets disjoint bufs
    if (sc < scL) FETCH(sc + 1);  // in flight across TWO compute sub-phases

    // sub-chunk 0 (always <= qtL since qtL odd)
    attn_phase(Ks[b0], Vts[b0], bqL, oL, lL, scale2, sub0 == qtL, wv, qd, l16);
    if (sub0 <= qtS)
      attn_phase(Ks[b0], Vts[b0], bqS, oS, lS, scale2, sub0 == qtS, wv, qd, l16);
    // sub-chunk 1
    if (sub1 <= qtL) {
      attn_phase(Ks[b1], Vts[b1], bqL, oL, lL, scale2, sub1 == qtL, wv, qd, l16);
      if (sub1 <= qtS)
        attn_phase(Ks[b1], Vts[b1], bqS, oS, lS, scale2, sub1 == qtS, wv, qd, l16);
    }
  }
#undef FETCH

  // epilogue: both tiles (L -> Ks[0] scratch, S -> Vts[0] scratch)
  lL += __shfl_xor(lL, 16); lL += __shfl_xor(lL, 32);
  lS += __shfl_xor(lS, 16); lS += __shfl_xor(lS, 32);
  float invL = 1.f / lL, invS = 1.f / lS;
  __syncthreads();
#pragma unroll
  for (int n2 = 0; n2 < 4; ++n2)
#pragma unroll
    for (int r = 0; r < 4; ++r) {
      Ks[0][(wv * 16 + l16) * ST + n2 * 16 + qd * 4 + r] = cvt1(oL[n2][r] * invL);
      Vts[0][(wv * 16 + l16) * ST + n2 * 16 + qd * 4 + r] = cvt1(oS[n2][r] * invS);
    }
  __syncthreads();
  {
    u16* dstL = &heads[(long)(bs0 + qtL * 64 + sr) * 512 + h * 64 + scg];
    *(bf16x8*)dstL = *(const bf16x8*)&Ks[0][sr * ST + scg];
    *(bf16x8*)(dstL + 8) = *(const bf16x8*)&Ks[0][sr * ST + scg + 8];
    u16* dstS = &heads[(long)(bs0 + qtS * 64 + sr) * 512 + h * 64 + scg];
    *(bf16x8*)dstS = *(const bf16x8*)&Vts[0][sr * ST + scg];
    *(bf16x8*)(dstS + 8) = *(const bf16x8*)&Vts[0][sr * ST + scg + 8];
  }
}

// cross-head normalization over H=8; heads bf16 [8192,512] -> hN bf16
__global__ __launch_bounds__(256) void headnorm(const u16* __restrict__ heads,
                                                const float* __restrict__ hm,
                                                u16* __restrict__ outn) {
  int i = blockIdx.x * 256 + threadIdx.x;
  int d = i & 63, bs = i >> 6;
  const u16* p = heads + (long)bs * DD + d;
  float x[NH], mean = 0.f;
#pragma unroll
  for (int h = 0; h < NH; ++h) { x[h] = bf2f(p[h * 64]); mean += x[h]; }
  mean *= 0.125f;
  float var = 0.f;
#pragma unroll
  for (int h = 0; h < NH; ++h) { float dd = x[h] - mean; var += dd * dd; }
  var *= 0.125f;
  float inv = 1.f / (sqrtf(var) + 0.01f);
#pragma unroll
  for (int h = 0; h < NH; ++h)
    outn[(long)bs * DD + h * 64 + d] = cvt1((x[h] - mean) * inv * hm[h]);
}

extern "C" void kernel_launch(void* const* d_in, const int* in_sizes, int n_in,
                              void* d_out, int out_size, void* d_ws, size_t ws_size,
                              hipStream_t stream) {
  const float* query = (const float*)d_in[0];
  const float* value = (const float*)d_in[1];
  // d_in[2] = mask: causal by construction -> applied analytically
  const float* Wq    = (const float*)d_in[3];
  const float* Wkv   = (const float*)d_in[4];
  const float* Wo    = (const float*)d_in[5];
  const float* normp = (const float*)d_in[6];
  const float* hmult = (const float*)d_in[7];

  char* ws = (char*)d_ws;
  const size_t MB = 1 << 20;
  u16*   WqT   = (u16*)(ws);                   //  0.5 MB
  u16*   WkvT  = (u16*)(ws + 524288);          //  1 MB
  u16*   WoT   = (u16*)(ws + 1 * MB + 524288); //  0.5 MB
  u16*   Qb    = (u16*)(ws + 2 * MB);          //  8 MB
  u16*   Kb    = (u16*)(ws + 10 * MB);         //  8 MB
  u16*   Vt    = (u16*)(ws + 18 * MB);         //  8 MB
  u16*   heads = (u16*)(ws + 26 * MB);         //  8 MB
  u16*   hN    = (u16*)(ws + 34 * MB);         //  8 MB (42 MB total)

  prep<<<256, 256, 0, stream>>>(Wq, Wkv, Wo, WqT, WkvT, WoT);
  qkv_gemm<<<dim3(64, 12), 256, 0, stream>>>(query, value, WqT, WkvT, Qb, Kb, Vt);
  attn<<<512, 256, 0, stream>>>(Qb, Kb, Vt, heads, normp);
  headnorm<<<(4 * BS * 64) / 256, 256, 0, stream>>>(heads, hmult, hN);
  out_gemm<<<dim3(64, 4), 256, 0, stream>>>(hN, WoT, (float*)d_out);
}